// Round 19
// baseline (551.983 us; speedup 1.0000x reference)
//
#include <hip/hip_runtime.h>

#define D 128
#define OUTD 384
#define SLOPE 0.2f
#define BSH 7                  // bucket = row >> 7  (128 rows/bucket)
#define BROWS 128
#define MAXNB 2048
#define FCAP 4736              // per-bucket capacity (avg 4096 + ~9 sigma slack)
#define SPAN 8192              // edges per scatter segment
#define FTH 512
#define NSMAX 1025
#define GR 64
#define APAD 136
#define GEMM_LDS (GR * APAD * 2 + 128 * APAD * 2)   // 52224 B

typedef __attribute__((ext_vector_type(8))) short bf16x8;
typedef __attribute__((ext_vector_type(4))) float f32x4;

__device__ __forceinline__ unsigned f2bf(float f) {   // round-to-nearest-even bf16
    unsigned u = __float_as_uint(f);
    return (u + 0x7FFFu + ((u >> 16) & 1u)) >> 16;
}

__device__ __forceinline__ void nt_store_f4(float4 v, float* p) {
    f32x4 t = {v.x, v.y, v.z, v.w};
    __builtin_nontemporal_store(t, (f32x4*)p);
}

// ================= device roles (512 threads each) =================

__device__ void dev_wtprep(const float* __restrict__ W, unsigned short* __restrict__ o) {
    for (int i = threadIdx.x; i < 16384; i += 512) {
        int k = i >> 7, n = i & 127;
        o[(size_t)n * 128 + k] = (unsigned short)f2bf(W[(size_t)k * 128 + n]);
    }
}

// ---- MFMA GEMM block (64 rows): featb = bf16((rowscale*in) @ W) ----
__device__ void dev_gemm(char* smem, const float* __restrict__ in, int pitch,
                         const unsigned short* __restrict__ Wt,
                         const float* __restrict__ Wraw,
                         unsigned short* __restrict__ featb,
                         const float* __restrict__ rowscale,
                         float* __restrict__ rawout,
                         int nrows, int blk) {
    unsigned short* sA = (unsigned short*)smem;            // 64 x APAD
    unsigned short* sW = sA + GR * APAD;                   // 128 x APAD
    int tid = threadIdx.x;
    int row0 = blk * GR;
    int nr = min(GR, nrows - row0);

    for (int i = tid; i < GR * 32; i += 512) {
        int r = i >> 5, c4 = (i & 31) * 4;
        unsigned lo = 0, hi = 0;
        if (r < nr) {
            float4 t = *(const float4*)&in[(size_t)(row0 + r) * pitch + c4];
            if (rawout)
                nt_store_f4(t, &rawout[(size_t)(row0 + r) * OUTD + c4]);
            if (rowscale) {
                float s = rowscale[row0 + r];
                t.x *= s; t.y *= s; t.z *= s; t.w *= s;
            }
            lo = f2bf(t.x) | (f2bf(t.y) << 16);
            hi = f2bf(t.z) | (f2bf(t.w) << 16);
        }
        uint2 pk = {lo, hi};
        *(uint2*)&sA[r * APAD + c4] = pk;
    }
    if (Wt) {
        for (int i = tid; i < 128 * 16; i += 512) {
            int n = i >> 4, k8 = (i & 15) * 8;
            *(uint4*)&sW[n * APAD + k8] = *(const uint4*)&Wt[(size_t)n * 128 + k8];
        }
    } else {
        for (int i = tid; i < 128 * 32; i += 512) {
            int k = i >> 5, c4 = (i & 31) * 4;
            float4 t = *(const float4*)&Wraw[(size_t)k * 128 + c4];
            sW[(c4 + 0) * APAD + k] = (unsigned short)f2bf(t.x);
            sW[(c4 + 1) * APAD + k] = (unsigned short)f2bf(t.y);
            sW[(c4 + 2) * APAD + k] = (unsigned short)f2bf(t.z);
            sW[(c4 + 3) * APAD + k] = (unsigned short)f2bf(t.w);
        }
    }
    __syncthreads();

    int l  = tid & 63;
    int w8 = tid >> 6;
    int rowTile = w8 >> 1;
    int colHalf = w8 & 1;
    int lr = l & 15;
    int lk = (l >> 4) * 8;

    f32x4 acc[4];
#pragma unroll
    for (int t = 0; t < 4; ++t) acc[t] = (f32x4){0.f, 0.f, 0.f, 0.f};

#pragma unroll
    for (int k0 = 0; k0 < 128; k0 += 32) {
        bf16x8 af = *(const bf16x8*)&sA[(16 * rowTile + lr) * APAD + k0 + lk];
#pragma unroll
        for (int t = 0; t < 4; ++t) {
            bf16x8 bf = *(const bf16x8*)&sW[((colHalf * 4 + t) * 16 + lr) * APAD + k0 + lk];
            acc[t] = __builtin_amdgcn_mfma_f32_16x16x32_bf16(af, bf, acc[t], 0, 0, 0);
        }
    }

    int rbase = 16 * rowTile + (l >> 4) * 4;
#pragma unroll
    for (int t = 0; t < 4; ++t) {
#pragma unroll
        for (int q = 0; q < 4; ++q) {
            int r = rbase + q;
            if (r < nr)
                featb[(size_t)(row0 + r) * D + (colHalf * 4 + t) * 16 + lr] =
                    (unsigned short)f2bf(acc[t][q]);
        }
    }
}

// ---- segment-local scatter block ----
__device__ void dev_scatter(char* smem,
                            const int* __restrict__ rows,
                            const int* __restrict__ cols,
                            const float* __restrict__ vals,
                            uint2* __restrict__ etmp,
                            int* __restrict__ offmat,
                            int nnz, int NB, int sgm) {
    int* hist = (int*)smem;
    int* wsum = hist + MAXNB;
    int tid = threadIdx.x;
    int lo  = sgm * SPAN;
    int hi  = min(lo + SPAN, nnz);
    if (lo >= nnz) return;

    for (int i = tid; i < NB; i += 512) hist[i] = 0;
    __syncthreads();

    int4 r4[4];
#pragma unroll
    for (int q = 0; q < 4; ++q) {
        int e = lo + (q * 512 + tid) * 4;
        if (e + 3 < hi) {
            r4[q] = *(const int4*)&rows[e];
            atomicAdd(&hist[r4[q].x >> BSH], 1);
            atomicAdd(&hist[r4[q].y >> BSH], 1);
            atomicAdd(&hist[r4[q].z >> BSH], 1);
            atomicAdd(&hist[r4[q].w >> BSH], 1);
        } else {
            int t0 = (e + 0 < hi) ? rows[e + 0] : -1;
            int t1 = (e + 1 < hi) ? rows[e + 1] : -1;
            int t2 = (e + 2 < hi) ? rows[e + 2] : -1;
            int t3 = (e + 3 < hi) ? rows[e + 3] : -1;
            if (t0 >= 0) atomicAdd(&hist[t0 >> BSH], 1);
            if (t1 >= 0) atomicAdd(&hist[t1 >> BSH], 1);
            if (t2 >= 0) atomicAdd(&hist[t2 >> BSH], 1);
            if (t3 >= 0) atomicAdd(&hist[t3 >> BSH], 1);
            r4[q] = make_int4(t0, t1, t2, t3);
        }
    }
    __syncthreads();

    int per = (NB + 511) / 512;
    int base = tid * per;
    int lv[4];
    int lsum = 0;
#pragma unroll
    for (int k = 0; k < 4; ++k) {
        int idx = base + k;
        int v = (k < per && idx < NB) ? hist[idx] : 0;
        lv[k] = v; lsum += v;
    }
    int lane = tid & 63, wid = tid >> 6;
    int incl = lsum;
#pragma unroll
    for (int off = 1; off < 64; off <<= 1) {
        int t = __shfl_up(incl, off);
        if (lane >= off) incl += t;
    }
    if (lane == 63) wsum[wid] = incl;
    __syncthreads();
    int woff = 0;
    for (int w = 0; w < wid; ++w) woff += wsum[w];
    int run = woff + incl - lsum;
    __syncthreads();
    int rowbase = sgm * (NB + 1);
#pragma unroll
    for (int k = 0; k < 4; ++k) {
        int idx = base + k;
        if (k < per && idx < NB) {
            int c = lv[k];
            hist[idx] = run;
            offmat[rowbase + idx] = run;
            run += c;
        }
    }
    if (NB - 1 >= base && NB - 1 < base + per)
        offmat[rowbase + NB] = run;
    __syncthreads();

#define SEMIT(r, c, v)                                                             \
    {                                                                              \
        int pos_ = atomicAdd(&hist[(r) >> BSH], 1);                                \
        etmp[lo + pos_] = make_uint2(((unsigned)((r) & (BROWS - 1)) << 18) |       \
                                     (unsigned)(c), __float_as_uint(v));           \
    }
#pragma unroll
    for (int q = 0; q < 4; ++q) {
        int e = lo + (q * 512 + tid) * 4;
        if (e + 3 < hi) {
            int4   c4 = *(const int4*)&cols[e];
            float4 v4 = *(const float4*)&vals[e];
            SEMIT(r4[q].x, c4.x, v4.x);
            SEMIT(r4[q].y, c4.y, v4.y);
            SEMIT(r4[q].z, c4.z, v4.z);
            SEMIT(r4[q].w, c4.w, v4.w);
        } else {
            int rr0 = r4[q].x, rr1 = r4[q].y, rr2 = r4[q].z, rr3 = r4[q].w;
            if (rr0 >= 0) { SEMIT(rr0, cols[e + 0], vals[e + 0]); }
            if (rr1 >= 0) { SEMIT(rr1, cols[e + 1], vals[e + 1]); }
            if (rr2 >= 0) { SEMIT(rr2, cols[e + 2], vals[e + 2]); }
            if (rr3 >= 0) { SEMIT(rr3, cols[e + 3], vals[e + 3]); }
        }
    }
#undef SEMIT
}

// ================= fused phase 1: scatter + wt_prep(L1) + gemm L0 =================
__global__ __launch_bounds__(512) void k_phase1(const int* rows, const int* cols,
                                                const float* vals, uint2* etmp,
                                                int* offmat, int nnz, int NB, int NS,
                                                const float* ue, const float* ie,
                                                const float* uw0, const float* vw0,
                                                const float* uw1, const float* vw1,
                                                unsigned short* wtbuf,
                                                unsigned short* featb, float* out,
                                                int U, int I, int gu) {
    extern __shared__ char smem[];
    int b = blockIdx.x;
    if (b < NS) {
        dev_scatter(smem, rows, cols, vals, etmp, offmat, nnz, NB, b);
    } else if (b < NS + 2) {
        dev_wtprep((b - NS == 0) ? uw1 : vw1, wtbuf + (size_t)(2 + (b - NS)) * 16384);
    } else if (b < NS + 2 + gu) {
        dev_gemm(smem, ue, D, nullptr, uw0, featb, nullptr, out, U, b - NS - 2);
    } else {
        dev_gemm(smem, ie, D, nullptr, vw0, featb + (size_t)U * D, nullptr,
                 out + (size_t)U * OUTD, I, b - NS - 2 - gu);
    }
}

// ================= fused layer-1 gemm (both halves, one dispatch) =================
__global__ __launch_bounds__(512) void k_gemm_l1(const float* out, const float* nsave,
                                                 const unsigned short* wtbuf,
                                                 unsigned short* featb,
                                                 int U, int I, int gu) {
    __shared__ char smem[GEMM_LDS];
    int b = blockIdx.x;
    if (b < gu) {
        dev_gemm(smem, out + D, OUTD, wtbuf + 2 * 16384, nullptr, featb,
                 nsave, nullptr, U, b);
    } else {
        dev_gemm(smem, out + (size_t)U * OUTD + D, OUTD, wtbuf + 3 * 16384, nullptr,
                 featb + (size_t)U * D, nsave + U, nullptr, I, b - gu);
    }
}

// ================= standalone kernels (serial fallback path) =================
__global__ __launch_bounds__(512) void k_gemm(const float* in, int pitch,
                                              const unsigned short* Wt,
                                              unsigned short* featb,
                                              const float* rowscale, float* rawout,
                                              int nrows) {
    __shared__ char smem[GEMM_LDS];
    dev_gemm(smem, in, pitch, Wt, nullptr, featb, rowscale, rawout, nrows, blockIdx.x);
}

__global__ __launch_bounds__(512) void k_wtprep4(const float* W0, const float* W1,
                                                 const float* W2, const float* W3,
                                                 unsigned short* wt) {
    const float* Ws[4] = {W0, W1, W2, W3};
    dev_wtprep(Ws[blockIdx.x], wt + (size_t)blockIdx.x * 16384);
}

__global__ __launch_bounds__(512) void k_scatter(const int* rows, const int* cols,
                                                 const float* vals, uint2* etmp,
                                                 int* offmat, int nnz, int NB) {
    extern __shared__ char smem[];
    dev_scatter(smem, rows, cols, vals, etmp, offmat, nnz, NB, blockIdx.x);
}

// ================= per-bucket gather + row sort (runs-of-8 forward-walk) =============
__global__ __launch_bounds__(FTH) void seg_finalize(const uint2* __restrict__ etmp,
                                                    const int* __restrict__ offmat,
                                                    uint2* __restrict__ esort,
                                                    int* __restrict__ row_start,
                                                    int* __restrict__ rend,
                                                    int N, int NB, int NS, int cap) {
    __shared__ uint2 ed[FCAP];
    __shared__ int srcoff[NSMAX], dstoff[NSMAX];
    __shared__ int rcnt[BROWS], rbase[BROWS];
    __shared__ int wsum[8];
    __shared__ int tot;
    int b   = blockIdx.x;
    int tid = threadIdx.x;
    int lane = tid & 63, wid = tid >> 6;
    if (tid < BROWS) rcnt[tid] = 0;

    int per = (NS + FTH - 1) / FTH;
    int base = tid * per;
    int lo0[2], ll[2];
    int lsum = 0;
#pragma unroll
    for (int k = 0; k < 2; ++k) {
        int s = base + k;
        int o0 = 0, l = 0;
        if (k < per && s < NS) {
            int rb = s * (NB + 1) + b;
            o0 = offmat[rb];
            l  = offmat[rb + 1] - o0;
        }
        lo0[k] = o0; ll[k] = l; lsum += l;
    }
    int incl = lsum;
#pragma unroll
    for (int off = 1; off < 64; off <<= 1) {
        int t = __shfl_up(incl, off);
        if (lane >= off) incl += t;
    }
    if (lane == 63) wsum[wid] = incl;
    __syncthreads();
    int woff = 0;
    for (int w = 0; w < wid; ++w) woff += wsum[w];
    int run = woff + incl - lsum;
#pragma unroll
    for (int k = 0; k < 2; ++k) {
        int s = base + k;
        if (k < per && s < NS) {
            srcoff[s] = lo0[k];
            dstoff[s] = run;
            run += ll[k];
        }
    }
    if (NS - 1 >= base && NS - 1 < base + per) {
        tot = min(run, cap);
        dstoff[NS] = run;
    }
    __syncthreads();

    // staging: each thread owns 8 consecutive dst slots; 1 binary search + forward walk
    int tl = tot;
    for (int d0 = tid * 8; d0 < tl; d0 += FTH * 8) {
        int s0 = 0, s1 = NS;
        while (s1 - s0 > 1) {
            int mid = (s0 + s1) >> 1;
            if (dstoff[mid] <= d0) s0 = mid; else s1 = mid;
        }
        int dEnd = min(d0 + 8, tl);
        int d = d0;
        while (d < dEnd) {
            while (dstoff[s0 + 1] <= d) ++s0;        // skip empty / advance chunk
            int cEnd = dstoff[s0 + 1];
            if (cEnd > dEnd) cEnd = dEnd;
            int src = s0 * SPAN + srcoff[s0] + (d - dstoff[s0]);
            for (; d < cEnd; ++d, ++src) {
                uint2 t = etmp[src];
                ed[d] = t;
                atomicAdd(&rcnt[t.x >> 18], 1);
            }
        }
    }
    __syncthreads();

    int c = (tid < BROWS) ? rcnt[tid] : 0;
    int incl2 = c;
#pragma unroll
    for (int off = 1; off < 64; off <<= 1) {
        int t = __shfl_up(incl2, off);
        if (lane >= off) incl2 += t;
    }
    if (tid < BROWS && lane == 63) wsum[wid] = incl2;
    __syncthreads();
    if (tid < BROWS) {
        int woff2 = (wid == 1) ? wsum[0] : 0;
        int excl = woff2 + incl2 - c;
        rbase[tid] = b * cap + excl;
        int row = b * BROWS + tid;
        if (row < N) { row_start[row] = b * cap + excl; rend[row] = b * cap + excl + c; }
    }
    __syncthreads();

    for (int d = tid; d < tl; d += FTH) {
        uint2 t = ed[d];
        int pos = atomicAdd(&rbase[t.x >> 18], 1);
        esort[pos] = make_uint2(t.x & 0x3FFFFu, t.y);
    }
}

// ================= CSR SpMM v4: wave per row, 4 edges per gather instruction ==========
#define ACCQ(vbits, g)                                             \
    {                                                              \
        float v = __uint_as_float(vbits);                          \
        acc0.x += v * __uint_as_float((g).x << 16);                \
        acc0.y += v * __uint_as_float((g).x & 0xFFFF0000u);        \
        acc0.z += v * __uint_as_float((g).y << 16);                \
        acc0.w += v * __uint_as_float((g).y & 0xFFFF0000u);        \
        acc1.x += v * __uint_as_float((g).z << 16);                \
        acc1.y += v * __uint_as_float((g).z & 0xFFFF0000u);        \
        acc1.z += v * __uint_as_float((g).w << 16);                \
        acc1.w += v * __uint_as_float((g).w & 0xFFFF0000u);        \
    }

__global__ __launch_bounds__(256) void spmm_csr4(const uint2* __restrict__ ep,
                                                 const int* __restrict__ rstart,
                                                 const int* __restrict__ rend,
                                                 const unsigned short* __restrict__ featb,
                                                 float* __restrict__ out,
                                                 float* __restrict__ nsave,
                                                 int col_off, int N) {
    int row  = blockIdx.x * 4 + (threadIdx.x >> 6);
    if (row >= N) return;
    int lane = threadIdx.x & 63;
    int j = lane & 15;
    int h = lane >> 4;
    int s = rstart[row], e = rend[row];

    float4 acc0 = {0.f, 0.f, 0.f, 0.f};
    float4 acc1 = {0.f, 0.f, 0.f, 0.f};
    int i = s;
    for (; i + 16 <= e; i += 16) {
        uint2 eA = ep[i + h];
        uint2 eB = ep[i + 4 + h];
        uint2 eC = ep[i + 8 + h];
        uint2 eD = ep[i + 12 + h];
        uint4 gA = *(const uint4*)&featb[(size_t)eA.x * D + j * 8];
        uint4 gB = *(const uint4*)&featb[(size_t)eB.x * D + j * 8];
        uint4 gC = *(const uint4*)&featb[(size_t)eC.x * D + j * 8];
        uint4 gD = *(const uint4*)&featb[(size_t)eD.x * D + j * 8];
        ACCQ(eA.y, gA);
        ACCQ(eB.y, gB);
        ACCQ(eC.y, gC);
        ACCQ(eD.y, gD);
    }
    for (; i + 8 <= e; i += 8) {
        uint2 eA = ep[i + h];
        uint2 eB = ep[i + 4 + h];
        uint4 gA = *(const uint4*)&featb[(size_t)eA.x * D + j * 8];
        uint4 gB = *(const uint4*)&featb[(size_t)eB.x * D + j * 8];
        ACCQ(eA.y, gA);
        ACCQ(eB.y, gB);
    }
    for (; i < e; i += 4) {
        int idx = i + h;
        uint2 ev = make_uint2(0u, 0u);
        if (idx < e) ev = ep[idx];
        uint4 g = *(const uint4*)&featb[(size_t)ev.x * D + j * 8];
        ACCQ(ev.y, g);
    }

#pragma unroll
    for (int m = 16; m <= 32; m <<= 1) {
        acc0.x += __shfl_xor(acc0.x, m);
        acc0.y += __shfl_xor(acc0.y, m);
        acc0.z += __shfl_xor(acc0.z, m);
        acc0.w += __shfl_xor(acc0.w, m);
        acc1.x += __shfl_xor(acc1.x, m);
        acc1.y += __shfl_xor(acc1.y, m);
        acc1.z += __shfl_xor(acc1.z, m);
        acc1.w += __shfl_xor(acc1.w, m);
    }

    acc0.x = (acc0.x > 0.f) ? acc0.x : SLOPE * acc0.x;
    acc0.y = (acc0.y > 0.f) ? acc0.y : SLOPE * acc0.y;
    acc0.z = (acc0.z > 0.f) ? acc0.z : SLOPE * acc0.z;
    acc0.w = (acc0.w > 0.f) ? acc0.w : SLOPE * acc0.w;
    acc1.x = (acc1.x > 0.f) ? acc1.x : SLOPE * acc1.x;
    acc1.y = (acc1.y > 0.f) ? acc1.y : SLOPE * acc1.y;
    acc1.z = (acc1.z > 0.f) ? acc1.z : SLOPE * acc1.z;
    acc1.w = (acc1.w > 0.f) ? acc1.w : SLOPE * acc1.w;

    float ss = acc0.x * acc0.x + acc0.y * acc0.y + acc0.z * acc0.z + acc0.w * acc0.w
             + acc1.x * acc1.x + acc1.y * acc1.y + acc1.z * acc1.z + acc1.w * acc1.w;
#pragma unroll
    for (int m = 8; m >= 1; m >>= 1) ss += __shfl_xor(ss, m);
    float nm = fmaxf(sqrtf(ss), 1e-12f);
    float sc = 1.0f / nm;

    if (nsave && lane == 0) nsave[row] = nm;
    if (h == 0) {
        float* dst = &out[(size_t)row * OUTD + col_off + j * 8];
        float4 o0 = {acc0.x * sc, acc0.y * sc, acc0.z * sc, acc0.w * sc};
        float4 o1 = {acc1.x * sc, acc1.y * sc, acc1.z * sc, acc1.w * sc};
        *(float4*)&dst[0] = o0;
        *(float4*)&dst[4] = o1;
    }
}

extern "C" void kernel_launch(void* const* d_in, const int* in_sizes, int n_in,
                              void* d_out, int out_size, void* d_ws, size_t ws_size,
                              hipStream_t stream) {
    const int*   rows = (const int*)d_in[0];
    const int*   cols = (const int*)d_in[1];
    const float* vals = (const float*)d_in[2];
    const float* ue   = (const float*)d_in[3];
    const float* ie   = (const float*)d_in[4];
    const float* uw0  = (const float*)d_in[5];
    const float* vw0  = (const float*)d_in[6];
    const float* uw1  = (const float*)d_in[7];
    const float* vw1  = (const float*)d_in[8];
    float* out = (float*)d_out;

    int nnz = in_sizes[0];
    int U   = in_sizes[3] / D;
    int I   = in_sizes[4] / D;
    int N   = U + I;
    int NB  = (N + BROWS - 1) >> BSH;
    int NS  = (nnz + SPAN - 1) / SPAN;

    int avg = nnz / NB;
    int cap = avg + avg / 8 + 64;
    if (cap > FCAP) cap = FCAP;

    int row_blocks = (N + 3) / 4;
    int gu = (U + GR - 1) / GR;
    int gi = (I + GR - 1) / GR;

    size_t featbSz = (size_t)N * D * 2;
    size_t etmpSz  = (size_t)NS * SPAN * 8;
    size_t esortSz = (size_t)NB * cap * 8;
    size_t miscSz  = (size_t)N * 12 + (size_t)NS * (NB + 1) * 4 + 4 * 16384 * 2 + 256;
    size_t needFused = featbSz + etmpSz + esortSz + miscSz;

    if (ws_size >= needFused) {
        char* p = (char*)d_ws;
        unsigned short* featb = (unsigned short*)p;  p += featbSz;
        uint2* etmp           = (uint2*)p;           p += etmpSz;
        uint2* esort          = (uint2*)p;           p += esortSz;
        int* row_start        = (int*)p;             p += (size_t)N * 4;
        int* rend             = (int*)p;             p += (size_t)N * 4;
        float* nsave          = (float*)p;           p += (size_t)N * 4;
        p = (char*)(((size_t)p + 63) & ~(size_t)63);
        int* offmat           = (int*)p;             p += (size_t)NS * (NB + 1) * 4;
        p = (char*)(((size_t)p + 63) & ~(size_t)63);
        unsigned short* wtbuf = (unsigned short*)p;

        k_phase1<<<NS + 2 + gu + gi, 512, GEMM_LDS, stream>>>(
            rows, cols, vals, etmp, offmat, nnz, NB, NS,
            ue, ie, uw0, vw0, uw1, vw1, wtbuf, featb, out, U, I, gu);

        seg_finalize<<<NB, FTH, 0, stream>>>(etmp, offmat, esort, row_start, rend,
                                             N, NB, NS, cap);
        spmm_csr4<<<row_blocks, 256, 0, stream>>>(esort, row_start, rend, featb, out,
                                                  nsave, D, N);

        k_gemm_l1<<<gu + gi, 512, 0, stream>>>(out, nsave, wtbuf, featb, U, I, gu);
        spmm_csr4<<<row_blocks, 256, 0, stream>>>(esort, row_start, rend, featb, out,
                                                  nullptr, 2 * D, N);
    } else {
        char* p = (char*)d_ws;
        size_t unionSz = featbSz > etmpSz ? featbSz : etmpSz;
        unsigned short* featb = (unsigned short*)p;
        uint2*          etmp  = (uint2*)p;           p += unionSz;
        uint2* esort          = (uint2*)p;           p += esortSz;
        int* row_start        = (int*)p;             p += (size_t)N * 4;
        int* rend             = (int*)p;             p += (size_t)N * 4;
        float* nsave          = (float*)p;           p += (size_t)N * 4;
        p = (char*)(((size_t)p + 63) & ~(size_t)63);
        int* offmat           = (int*)p;             p += (size_t)NS * (NB + 1) * 4;
        p = (char*)(((size_t)p + 63) & ~(size_t)63);
        unsigned short* wtbuf = (unsigned short*)p;

        k_wtprep4<<<4, 512, 0, stream>>>(uw0, vw0, uw1, vw1, wtbuf);
        k_scatter<<<NS, 512, MAXNB * 4 + 64, stream>>>(rows, cols, vals, etmp, offmat,
                                                       nnz, NB);
        seg_finalize<<<NB, FTH, 0, stream>>>(etmp, offmat, esort, row_start, rend,
                                             N, NB, NS, cap);

        k_gemm<<<gu, 512, 0, stream>>>(ue, D, wtbuf, featb, nullptr, out, U);
        k_gemm<<<gi, 512, 0, stream>>>(ie, D, wtbuf + 16384, featb + (size_t)U * D,
                                       nullptr, out + (size_t)U * OUTD, I);
        spmm_csr4<<<row_blocks, 256, 0, stream>>>(esort, row_start, rend, featb, out,
                                                  nsave, D, N);

        k_gemm_l1<<<gu + gi, 512, 0, stream>>>(out, nsave, wtbuf, featb, U, I, gu);
        spmm_csr4<<<row_blocks, 256, 0, stream>>>(esort, row_start, rend, featb, out,
                                                  nullptr, 2 * D, N);
    }
}

// Round 20
// 518.868 us; speedup vs baseline: 1.0638x; 1.0638x over previous
//
#include <hip/hip_runtime.h>

#define D 128
#define OUTD 384
#define SLOPE 0.2f
#define BSH 7                  // bucket = row >> 7  (128 rows/bucket)
#define BROWS 128
#define MAXNB 2048
#define FCAP 4736              // per-bucket capacity (avg 4096 + ~9 sigma slack)
#define SPAN 8192              // edges per scatter segment
#define FTH 512
#define NSMAX 1025
#define GR 64
#define APAD 136
#define GEMM_LDS (GR * APAD * 2 + 128 * APAD * 2)   // 52224 B

typedef __attribute__((ext_vector_type(8))) short bf16x8;
typedef __attribute__((ext_vector_type(4))) float f32x4;

__device__ __forceinline__ unsigned f2bf(float f) {   // round-to-nearest-even bf16
    unsigned u = __float_as_uint(f);
    return (u + 0x7FFFu + ((u >> 16) & 1u)) >> 16;
}

__device__ __forceinline__ void nt_store_f4(float4 v, float* p) {
    f32x4 t = {v.x, v.y, v.z, v.w};
    __builtin_nontemporal_store(t, (f32x4*)p);
}

// ================= device roles (512 threads each) =================

__device__ void dev_wtprep(const float* __restrict__ W, unsigned short* __restrict__ o) {
    for (int i = threadIdx.x; i < 16384; i += 512) {
        int k = i >> 7, n = i & 127;
        o[(size_t)n * 128 + k] = (unsigned short)f2bf(W[(size_t)k * 128 + n]);
    }
}

// ---- MFMA GEMM block (64 rows): featb = bf16((rowscale*in) @ W) ----
__device__ void dev_gemm(char* smem, const float* __restrict__ in, int pitch,
                         const unsigned short* __restrict__ Wt,
                         const float* __restrict__ Wraw,
                         unsigned short* __restrict__ featb,
                         const float* __restrict__ rowscale,
                         float* __restrict__ rawout,
                         int nrows, int blk) {
    unsigned short* sA = (unsigned short*)smem;            // 64 x APAD
    unsigned short* sW = sA + GR * APAD;                   // 128 x APAD
    int tid = threadIdx.x;
    int row0 = blk * GR;
    int nr = min(GR, nrows - row0);

    for (int i = tid; i < GR * 32; i += 512) {
        int r = i >> 5, c4 = (i & 31) * 4;
        unsigned lo = 0, hi = 0;
        if (r < nr) {
            float4 t = *(const float4*)&in[(size_t)(row0 + r) * pitch + c4];
            if (rawout)
                nt_store_f4(t, &rawout[(size_t)(row0 + r) * OUTD + c4]);
            if (rowscale) {
                float s = rowscale[row0 + r];
                t.x *= s; t.y *= s; t.z *= s; t.w *= s;
            }
            lo = f2bf(t.x) | (f2bf(t.y) << 16);
            hi = f2bf(t.z) | (f2bf(t.w) << 16);
        }
        uint2 pk = {lo, hi};
        *(uint2*)&sA[r * APAD + c4] = pk;
    }
    if (Wt) {
        for (int i = tid; i < 128 * 16; i += 512) {
            int n = i >> 4, k8 = (i & 15) * 8;
            *(uint4*)&sW[n * APAD + k8] = *(const uint4*)&Wt[(size_t)n * 128 + k8];
        }
    } else {
        for (int i = tid; i < 128 * 32; i += 512) {
            int k = i >> 5, c4 = (i & 31) * 4;
            float4 t = *(const float4*)&Wraw[(size_t)k * 128 + c4];
            sW[(c4 + 0) * APAD + k] = (unsigned short)f2bf(t.x);
            sW[(c4 + 1) * APAD + k] = (unsigned short)f2bf(t.y);
            sW[(c4 + 2) * APAD + k] = (unsigned short)f2bf(t.z);
            sW[(c4 + 3) * APAD + k] = (unsigned short)f2bf(t.w);
        }
    }
    __syncthreads();

    int l  = tid & 63;
    int w8 = tid >> 6;
    int rowTile = w8 >> 1;
    int colHalf = w8 & 1;
    int lr = l & 15;
    int lk = (l >> 4) * 8;

    f32x4 acc[4];
#pragma unroll
    for (int t = 0; t < 4; ++t) acc[t] = (f32x4){0.f, 0.f, 0.f, 0.f};

#pragma unroll
    for (int k0 = 0; k0 < 128; k0 += 32) {
        bf16x8 af = *(const bf16x8*)&sA[(16 * rowTile + lr) * APAD + k0 + lk];
#pragma unroll
        for (int t = 0; t < 4; ++t) {
            bf16x8 bf = *(const bf16x8*)&sW[((colHalf * 4 + t) * 16 + lr) * APAD + k0 + lk];
            acc[t] = __builtin_amdgcn_mfma_f32_16x16x32_bf16(af, bf, acc[t], 0, 0, 0);
        }
    }

    int rbase = 16 * rowTile + (l >> 4) * 4;
#pragma unroll
    for (int t = 0; t < 4; ++t) {
#pragma unroll
        for (int q = 0; q < 4; ++q) {
            int r = rbase + q;
            if (r < nr)
                featb[(size_t)(row0 + r) * D + (colHalf * 4 + t) * 16 + lr] =
                    (unsigned short)f2bf(acc[t][q]);
        }
    }
}

// ---- segment-local scatter block ----
__device__ void dev_scatter(char* smem,
                            const int* __restrict__ rows,
                            const int* __restrict__ cols,
                            const float* __restrict__ vals,
                            uint2* __restrict__ etmp,
                            int* __restrict__ offmat,
                            int nnz, int NB, int sgm) {
    int* hist = (int*)smem;
    int* wsum = hist + MAXNB;
    int tid = threadIdx.x;
    int lo  = sgm * SPAN;
    int hi  = min(lo + SPAN, nnz);
    if (lo >= nnz) return;

    for (int i = tid; i < NB; i += 512) hist[i] = 0;
    __syncthreads();

    int4 r4[4];
#pragma unroll
    for (int q = 0; q < 4; ++q) {
        int e = lo + (q * 512 + tid) * 4;
        if (e + 3 < hi) {
            r4[q] = *(const int4*)&rows[e];
            atomicAdd(&hist[r4[q].x >> BSH], 1);
            atomicAdd(&hist[r4[q].y >> BSH], 1);
            atomicAdd(&hist[r4[q].z >> BSH], 1);
            atomicAdd(&hist[r4[q].w >> BSH], 1);
        } else {
            int t0 = (e + 0 < hi) ? rows[e + 0] : -1;
            int t1 = (e + 1 < hi) ? rows[e + 1] : -1;
            int t2 = (e + 2 < hi) ? rows[e + 2] : -1;
            int t3 = (e + 3 < hi) ? rows[e + 3] : -1;
            if (t0 >= 0) atomicAdd(&hist[t0 >> BSH], 1);
            if (t1 >= 0) atomicAdd(&hist[t1 >> BSH], 1);
            if (t2 >= 0) atomicAdd(&hist[t2 >> BSH], 1);
            if (t3 >= 0) atomicAdd(&hist[t3 >> BSH], 1);
            r4[q] = make_int4(t0, t1, t2, t3);
        }
    }
    __syncthreads();

    int per = (NB + 511) / 512;
    int base = tid * per;
    int lv[4];
    int lsum = 0;
#pragma unroll
    for (int k = 0; k < 4; ++k) {
        int idx = base + k;
        int v = (k < per && idx < NB) ? hist[idx] : 0;
        lv[k] = v; lsum += v;
    }
    int lane = tid & 63, wid = tid >> 6;
    int incl = lsum;
#pragma unroll
    for (int off = 1; off < 64; off <<= 1) {
        int t = __shfl_up(incl, off);
        if (lane >= off) incl += t;
    }
    if (lane == 63) wsum[wid] = incl;
    __syncthreads();
    int woff = 0;
    for (int w = 0; w < wid; ++w) woff += wsum[w];
    int run = woff + incl - lsum;
    __syncthreads();
    int rowbase = sgm * (NB + 1);
#pragma unroll
    for (int k = 0; k < 4; ++k) {
        int idx = base + k;
        if (k < per && idx < NB) {
            int c = lv[k];
            hist[idx] = run;
            offmat[rowbase + idx] = run;
            run += c;
        }
    }
    if (NB - 1 >= base && NB - 1 < base + per)
        offmat[rowbase + NB] = run;
    __syncthreads();

#define SEMIT(r, c, v)                                                             \
    {                                                                              \
        int pos_ = atomicAdd(&hist[(r) >> BSH], 1);                                \
        etmp[lo + pos_] = make_uint2(((unsigned)((r) & (BROWS - 1)) << 18) |       \
                                     (unsigned)(c), __float_as_uint(v));           \
    }
#pragma unroll
    for (int q = 0; q < 4; ++q) {
        int e = lo + (q * 512 + tid) * 4;
        if (e + 3 < hi) {
            int4   c4 = *(const int4*)&cols[e];
            float4 v4 = *(const float4*)&vals[e];
            SEMIT(r4[q].x, c4.x, v4.x);
            SEMIT(r4[q].y, c4.y, v4.y);
            SEMIT(r4[q].z, c4.z, v4.z);
            SEMIT(r4[q].w, c4.w, v4.w);
        } else {
            int rr0 = r4[q].x, rr1 = r4[q].y, rr2 = r4[q].z, rr3 = r4[q].w;
            if (rr0 >= 0) { SEMIT(rr0, cols[e + 0], vals[e + 0]); }
            if (rr1 >= 0) { SEMIT(rr1, cols[e + 1], vals[e + 1]); }
            if (rr2 >= 0) { SEMIT(rr2, cols[e + 2], vals[e + 2]); }
            if (rr3 >= 0) { SEMIT(rr3, cols[e + 3], vals[e + 3]); }
        }
    }
#undef SEMIT
}

// ================= fused phase 1: scatter + wt_prep(L1) + gemm L0 =================
__global__ __launch_bounds__(512) void k_phase1(const int* rows, const int* cols,
                                                const float* vals, uint2* etmp,
                                                int* offmat, int nnz, int NB, int NS,
                                                const float* ue, const float* ie,
                                                const float* uw0, const float* vw0,
                                                const float* uw1, const float* vw1,
                                                unsigned short* wtbuf,
                                                unsigned short* featb, float* out,
                                                int U, int I, int gu) {
    extern __shared__ char smem[];
    int b = blockIdx.x;
    if (b < NS) {
        dev_scatter(smem, rows, cols, vals, etmp, offmat, nnz, NB, b);
    } else if (b < NS + 2) {
        dev_wtprep((b - NS == 0) ? uw1 : vw1, wtbuf + (size_t)(2 + (b - NS)) * 16384);
    } else if (b < NS + 2 + gu) {
        dev_gemm(smem, ue, D, nullptr, uw0, featb, nullptr, out, U, b - NS - 2);
    } else {
        dev_gemm(smem, ie, D, nullptr, vw0, featb + (size_t)U * D, nullptr,
                 out + (size_t)U * OUTD, I, b - NS - 2 - gu);
    }
}

// ================= fused layer-1 gemm (both halves, one dispatch) =================
__global__ __launch_bounds__(512) void k_gemm_l1(const float* out, const float* nsave,
                                                 const unsigned short* wtbuf,
                                                 unsigned short* featb,
                                                 int U, int I, int gu) {
    __shared__ char smem[GEMM_LDS];
    int b = blockIdx.x;
    if (b < gu) {
        dev_gemm(smem, out + D, OUTD, wtbuf + 2 * 16384, nullptr, featb,
                 nsave, nullptr, U, b);
    } else {
        dev_gemm(smem, out + (size_t)U * OUTD + D, OUTD, wtbuf + 3 * 16384, nullptr,
                 featb + (size_t)U * D, nsave + U, nullptr, I, b - gu);
    }
}

// ================= standalone kernels (serial fallback path) =================
__global__ __launch_bounds__(512) void k_gemm(const float* in, int pitch,
                                              const unsigned short* Wt,
                                              unsigned short* featb,
                                              const float* rowscale, float* rawout,
                                              int nrows) {
    __shared__ char smem[GEMM_LDS];
    dev_gemm(smem, in, pitch, Wt, nullptr, featb, rowscale, rawout, nrows, blockIdx.x);
}

__global__ __launch_bounds__(512) void k_wtprep4(const float* W0, const float* W1,
                                                 const float* W2, const float* W3,
                                                 unsigned short* wt) {
    const float* Ws[4] = {W0, W1, W2, W3};
    dev_wtprep(Ws[blockIdx.x], wt + (size_t)blockIdx.x * 16384);
}

__global__ __launch_bounds__(512) void k_scatter(const int* rows, const int* cols,
                                                 const float* vals, uint2* etmp,
                                                 int* offmat, int nnz, int NB) {
    extern __shared__ char smem[];
    dev_scatter(smem, rows, cols, vals, etmp, offmat, nnz, NB, blockIdx.x);
}

// ================= per-bucket gather + row sort (R18 edge-parallel staging) ===========
__global__ __launch_bounds__(FTH) void seg_finalize(const uint2* __restrict__ etmp,
                                                    const int* __restrict__ offmat,
                                                    uint2* __restrict__ esort,
                                                    int* __restrict__ row_start,
                                                    int* __restrict__ rend,
                                                    int N, int NB, int NS, int cap) {
    __shared__ uint2 ed[FCAP];
    __shared__ int srcoff[NSMAX], dstoff[NSMAX];
    __shared__ int rcnt[BROWS], rbase[BROWS];
    __shared__ int wsum[8];
    __shared__ int tot;
    int b   = blockIdx.x;
    int tid = threadIdx.x;
    int lane = tid & 63, wid = tid >> 6;
    if (tid < BROWS) rcnt[tid] = 0;

    int per = (NS + FTH - 1) / FTH;
    int base = tid * per;
    int lo0[2], ll[2];
    int lsum = 0;
#pragma unroll
    for (int k = 0; k < 2; ++k) {
        int s = base + k;
        int o0 = 0, l = 0;
        if (k < per && s < NS) {
            int rb = s * (NB + 1) + b;
            o0 = offmat[rb];
            l  = offmat[rb + 1] - o0;
        }
        lo0[k] = o0; ll[k] = l; lsum += l;
    }
    int incl = lsum;
#pragma unroll
    for (int off = 1; off < 64; off <<= 1) {
        int t = __shfl_up(incl, off);
        if (lane >= off) incl += t;
    }
    if (lane == 63) wsum[wid] = incl;
    __syncthreads();
    int woff = 0;
    for (int w = 0; w < wid; ++w) woff += wsum[w];
    int run = woff + incl - lsum;
#pragma unroll
    for (int k = 0; k < 2; ++k) {
        int s = base + k;
        if (k < per && s < NS) {
            srcoff[s] = lo0[k];
            dstoff[s] = run;
            run += ll[k];
        }
    }
    if (NS - 1 >= base && NS - 1 < base + per) {
        tot = min(run, cap);
        dstoff[NS] = run;
    }
    __syncthreads();

    // edge-parallel staging: per-edge binary search (wave reads consecutive dst slots)
    int tl = tot;
    for (int d = tid; d < tl; d += FTH) {
        int s0 = 0, s1 = NS;
        while (s1 - s0 > 1) {
            int mid = (s0 + s1) >> 1;
            if (dstoff[mid] <= d) s0 = mid; else s1 = mid;
        }
        int src = s0 * SPAN + srcoff[s0] + (d - dstoff[s0]);
        uint2 t = etmp[src];
        ed[d] = t;
        atomicAdd(&rcnt[t.x >> 18], 1);
    }
    __syncthreads();

    int c = (tid < BROWS) ? rcnt[tid] : 0;
    int incl2 = c;
#pragma unroll
    for (int off = 1; off < 64; off <<= 1) {
        int t = __shfl_up(incl2, off);
        if (lane >= off) incl2 += t;
    }
    if (tid < BROWS && lane == 63) wsum[wid] = incl2;
    __syncthreads();
    if (tid < BROWS) {
        int woff2 = (wid == 1) ? wsum[0] : 0;
        int excl = woff2 + incl2 - c;
        rbase[tid] = b * cap + excl;
        int row = b * BROWS + tid;
        if (row < N) { row_start[row] = b * cap + excl; rend[row] = b * cap + excl + c; }
    }
    __syncthreads();

    for (int d = tid; d < tl; d += FTH) {
        uint2 t = ed[d];
        int pos = atomicAdd(&rbase[t.x >> 18], 1);
        esort[pos] = make_uint2(t.x & 0x3FFFFu, t.y);
    }
}

// ================= CSR SpMM v4: wave per row, 4 edges per gather instruction ==========
#define ACCQ(vbits, g)                                             \
    {                                                              \
        float v = __uint_as_float(vbits);                          \
        acc0.x += v * __uint_as_float((g).x << 16);                \
        acc0.y += v * __uint_as_float((g).x & 0xFFFF0000u);        \
        acc0.z += v * __uint_as_float((g).y << 16);                \
        acc0.w += v * __uint_as_float((g).y & 0xFFFF0000u);        \
        acc1.x += v * __uint_as_float((g).z << 16);                \
        acc1.y += v * __uint_as_float((g).z & 0xFFFF0000u);        \
        acc1.z += v * __uint_as_float((g).w << 16);                \
        acc1.w += v * __uint_as_float((g).w & 0xFFFF0000u);        \
    }

__global__ __launch_bounds__(256) void spmm_csr4(const uint2* __restrict__ ep,
                                                 const int* __restrict__ rstart,
                                                 const int* __restrict__ rend,
                                                 const unsigned short* __restrict__ featb,
                                                 float* __restrict__ out,
                                                 float* __restrict__ nsave,
                                                 int col_off, int N) {
    int row  = blockIdx.x * 4 + (threadIdx.x >> 6);
    if (row >= N) return;
    int lane = threadIdx.x & 63;
    int j = lane & 15;
    int h = lane >> 4;
    int s = rstart[row], e = rend[row];

    float4 acc0 = {0.f, 0.f, 0.f, 0.f};
    float4 acc1 = {0.f, 0.f, 0.f, 0.f};
    int i = s;
    for (; i + 16 <= e; i += 16) {
        uint2 eA = ep[i + h];
        uint2 eB = ep[i + 4 + h];
        uint2 eC = ep[i + 8 + h];
        uint2 eD = ep[i + 12 + h];
        uint4 gA = *(const uint4*)&featb[(size_t)eA.x * D + j * 8];
        uint4 gB = *(const uint4*)&featb[(size_t)eB.x * D + j * 8];
        uint4 gC = *(const uint4*)&featb[(size_t)eC.x * D + j * 8];
        uint4 gD = *(const uint4*)&featb[(size_t)eD.x * D + j * 8];
        ACCQ(eA.y, gA);
        ACCQ(eB.y, gB);
        ACCQ(eC.y, gC);
        ACCQ(eD.y, gD);
    }
    for (; i + 8 <= e; i += 8) {
        uint2 eA = ep[i + h];
        uint2 eB = ep[i + 4 + h];
        uint4 gA = *(const uint4*)&featb[(size_t)eA.x * D + j * 8];
        uint4 gB = *(const uint4*)&featb[(size_t)eB.x * D + j * 8];
        ACCQ(eA.y, gA);
        ACCQ(eB.y, gB);
    }
    for (; i < e; i += 4) {
        int idx = i + h;
        uint2 ev = make_uint2(0u, 0u);
        if (idx < e) ev = ep[idx];
        uint4 g = *(const uint4*)&featb[(size_t)ev.x * D + j * 8];
        ACCQ(ev.y, g);
    }

#pragma unroll
    for (int m = 16; m <= 32; m <<= 1) {
        acc0.x += __shfl_xor(acc0.x, m);
        acc0.y += __shfl_xor(acc0.y, m);
        acc0.z += __shfl_xor(acc0.z, m);
        acc0.w += __shfl_xor(acc0.w, m);
        acc1.x += __shfl_xor(acc1.x, m);
        acc1.y += __shfl_xor(acc1.y, m);
        acc1.z += __shfl_xor(acc1.z, m);
        acc1.w += __shfl_xor(acc1.w, m);
    }

    acc0.x = (acc0.x > 0.f) ? acc0.x : SLOPE * acc0.x;
    acc0.y = (acc0.y > 0.f) ? acc0.y : SLOPE * acc0.y;
    acc0.z = (acc0.z > 0.f) ? acc0.z : SLOPE * acc0.z;
    acc0.w = (acc0.w > 0.f) ? acc0.w : SLOPE * acc0.w;
    acc1.x = (acc1.x > 0.f) ? acc1.x : SLOPE * acc1.x;
    acc1.y = (acc1.y > 0.f) ? acc1.y : SLOPE * acc1.y;
    acc1.z = (acc1.z > 0.f) ? acc1.z : SLOPE * acc1.z;
    acc1.w = (acc1.w > 0.f) ? acc1.w : SLOPE * acc1.w;

    float ss = acc0.x * acc0.x + acc0.y * acc0.y + acc0.z * acc0.z + acc0.w * acc0.w
             + acc1.x * acc1.x + acc1.y * acc1.y + acc1.z * acc1.z + acc1.w * acc1.w;
#pragma unroll
    for (int m = 8; m >= 1; m >>= 1) ss += __shfl_xor(ss, m);
    float nm = fmaxf(sqrtf(ss), 1e-12f);
    float sc = 1.0f / nm;

    if (nsave && lane == 0) nsave[row] = nm;
    if (h == 0) {
        float* dst = &out[(size_t)row * OUTD + col_off + j * 8];
        float4 o0 = {acc0.x * sc, acc0.y * sc, acc0.z * sc, acc0.w * sc};
        float4 o1 = {acc1.x * sc, acc1.y * sc, acc1.z * sc, acc1.w * sc};
        *(float4*)&dst[0] = o0;
        *(float4*)&dst[4] = o1;
    }
}

extern "C" void kernel_launch(void* const* d_in, const int* in_sizes, int n_in,
                              void* d_out, int out_size, void* d_ws, size_t ws_size,
                              hipStream_t stream) {
    const int*   rows = (const int*)d_in[0];
    const int*   cols = (const int*)d_in[1];
    const float* vals = (const float*)d_in[2];
    const float* ue   = (const float*)d_in[3];
    const float* ie   = (const float*)d_in[4];
    const float* uw0  = (const float*)d_in[5];
    const float* vw0  = (const float*)d_in[6];
    const float* uw1  = (const float*)d_in[7];
    const float* vw1  = (const float*)d_in[8];
    float* out = (float*)d_out;

    int nnz = in_sizes[0];
    int U   = in_sizes[3] / D;
    int I   = in_sizes[4] / D;
    int N   = U + I;
    int NB  = (N + BROWS - 1) >> BSH;
    int NS  = (nnz + SPAN - 1) / SPAN;

    int avg = nnz / NB;
    int cap = avg + avg / 8 + 64;
    if (cap > FCAP) cap = FCAP;

    int row_blocks = (N + 3) / 4;
    int gu = (U + GR - 1) / GR;
    int gi = (I + GR - 1) / GR;

    size_t featbSz = (size_t)N * D * 2;
    size_t etmpSz  = (size_t)NS * SPAN * 8;
    size_t esortSz = (size_t)NB * cap * 8;
    size_t miscSz  = (size_t)N * 12 + (size_t)NS * (NB + 1) * 4 + 4 * 16384 * 2 + 256;
    size_t needFused = featbSz + etmpSz + esortSz + miscSz;

    if (ws_size >= needFused) {
        char* p = (char*)d_ws;
        unsigned short* featb = (unsigned short*)p;  p += featbSz;
        uint2* etmp           = (uint2*)p;           p += etmpSz;
        uint2* esort          = (uint2*)p;           p += esortSz;
        int* row_start        = (int*)p;             p += (size_t)N * 4;
        int* rend             = (int*)p;             p += (size_t)N * 4;
        float* nsave          = (float*)p;           p += (size_t)N * 4;
        p = (char*)(((size_t)p + 63) & ~(size_t)63);
        int* offmat           = (int*)p;             p += (size_t)NS * (NB + 1) * 4;
        p = (char*)(((size_t)p + 63) & ~(size_t)63);
        unsigned short* wtbuf = (unsigned short*)p;

        k_phase1<<<NS + 2 + gu + gi, 512, GEMM_LDS, stream>>>(
            rows, cols, vals, etmp, offmat, nnz, NB, NS,
            ue, ie, uw0, vw0, uw1, vw1, wtbuf, featb, out, U, I, gu);

        seg_finalize<<<NB, FTH, 0, stream>>>(etmp, offmat, esort, row_start, rend,
                                             N, NB, NS, cap);
        spmm_csr4<<<row_blocks, 256, 0, stream>>>(esort, row_start, rend, featb, out,
                                                  nsave, D, N);

        k_gemm_l1<<<gu + gi, 512, 0, stream>>>(out, nsave, wtbuf, featb, U, I, gu);
        spmm_csr4<<<row_blocks, 256, 0, stream>>>(esort, row_start, rend, featb, out,
                                                  nullptr, 2 * D, N);
    } else {
        char* p = (char*)d_ws;
        size_t unionSz = featbSz > etmpSz ? featbSz : etmpSz;
        unsigned short* featb = (unsigned short*)p;
        uint2*          etmp  = (uint2*)p;           p += unionSz;
        uint2* esort          = (uint2*)p;           p += esortSz;
        int* row_start        = (int*)p;             p += (size_t)N * 4;
        int* rend             = (int*)p;             p += (size_t)N * 4;
        float* nsave          = (float*)p;           p += (size_t)N * 4;
        p = (char*)(((size_t)p + 63) & ~(size_t)63);
        int* offmat           = (int*)p;             p += (size_t)NS * (NB + 1) * 4;
        p = (char*)(((size_t)p + 63) & ~(size_t)63);
        unsigned short* wtbuf = (unsigned short*)p;

        k_wtprep4<<<4, 512, 0, stream>>>(uw0, vw0, uw1, vw1, wtbuf);
        k_scatter<<<NS, 512, MAXNB * 4 + 64, stream>>>(rows, cols, vals, etmp, offmat,
                                                       nnz, NB);
        seg_finalize<<<NB, FTH, 0, stream>>>(etmp, offmat, esort, row_start, rend,
                                             N, NB, NS, cap);

        k_gemm<<<gu, 512, 0, stream>>>(ue, D, wtbuf, featb, nullptr, out, U);
        k_gemm<<<gi, 512, 0, stream>>>(ie, D, wtbuf + 16384, featb + (size_t)U * D,
                                       nullptr, out + (size_t)U * OUTD, I);
        spmm_csr4<<<row_blocks, 256, 0, stream>>>(esort, row_start, rend, featb, out,
                                                  nsave, D, N);

        k_gemm_l1<<<gu + gi, 512, 0, stream>>>(out, nsave, wtbuf, featb, U, I, gu);
        spmm_csr4<<<row_blocks, 256, 0, stream>>>(esort, row_start, rend, featb, out,
                                                  nullptr, 2 * D, N);
    }
}